// Round 10
// baseline (183.228 us; speedup 1.0000x reference)
//
#include <hip/hip_runtime.h>
#include <hip/hip_bf16.h>

typedef __attribute__((ext_vector_type(4))) float f32x4;
typedef __attribute__((ext_vector_type(8))) short bf16x8;
typedef __attribute__((ext_vector_type(4))) int i32x4;

#define GS 128

#define GLOAD_LDS16(g, l)                                                        \
    __builtin_amdgcn_global_load_lds(                                            \
        (const __attribute__((address_space(1))) void*)(g),                      \
        (__attribute__((address_space(3))) void*)(l), 16, 0, 0)

__device__ __forceinline__ short f2bf(float f) {
    union { float f; unsigned u; } v; v.f = f;
    unsigned r = v.u + 0x7fffu + ((v.u >> 16) & 1u);
    return (short)(r >> 16);
}

// ---------------- fused prep: W requant (blocks [0,N)) + X quant (blocks [N,N+M)) ----
__global__ void prep_kernel(const int* __restrict__ QW,
                            const float* __restrict__ SC,
                            const int* __restrict__ ZR,
                            const float* __restrict__ X,
                            signed char* __restrict__ W8,
                            float* __restrict__ WS,
                            signed char* __restrict__ Xq,
                            float* __restrict__ XS,
                            int N, int K, int G) {
    const int tid = threadIdx.x;             // 256 threads
    const int lane = tid & 63;
    const int wid = tid >> 6;
    __shared__ float red[4];

    if ((int)blockIdx.x < N) {
        // ---- per-row W requant -> int8 with per-row scale ----
        const int o = blockIdx.x;
        const int g = tid / 8;               // (tid*16)/128
        const float s = SC[(long)o * G + g];
        const float z = (float)ZR[(long)o * G + g];
        const int* p = QW + (long)o * (K / 2) + tid * 8;
        int v[8];
#pragma unroll
        for (int j = 0; j < 8; ++j) v[j] = p[j];
        float w[16];
#pragma unroll
        for (int j = 0; j < 8; ++j) {
            w[2 * j]     = ((float)(v[j] & 15) - z) * s;
            w[2 * j + 1] = ((float)((v[j] >> 4) & 15) - z) * s;
        }
        float am = 0.f;
#pragma unroll
        for (int j = 0; j < 16; ++j) am = fmaxf(am, fabsf(w[j]));
#pragma unroll
        for (int off = 32; off >= 1; off >>= 1) am = fmaxf(am, __shfl_xor(am, off));
        if (lane == 0) red[wid] = am;
        __syncthreads();
        float wmax = fmaxf(fmaxf(red[0], red[1]), fmaxf(red[2], red[3]));
        wmax = fmaxf(wmax, 1e-30f);
        const float qs = 127.0f / wmax;
        int out[4];
#pragma unroll
        for (int j = 0; j < 4; ++j) {
            int b0 = ((int)rintf(w[4 * j]     * qs)) & 255;
            int b1 = ((int)rintf(w[4 * j + 1] * qs)) & 255;
            int b2 = ((int)rintf(w[4 * j + 2] * qs)) & 255;
            int b3 = ((int)rintf(w[4 * j + 3] * qs)) & 255;
            out[j] = b0 | (b1 << 8) | (b2 << 16) | (b3 << 24);
        }
        *(i32x4*)(W8 + (long)o * K + tid * 16) = *(i32x4*)out;
        if (tid == 0) WS[o] = wmax / 127.0f;
    } else {
        // ---- per-row dynamic int8 quant of X ----
        const int row = blockIdx.x - N;
        const float* px = X + (long)row * K + tid * 16;
        f32x4 v[4];
#pragma unroll
        for (int j = 0; j < 4; ++j) v[j] = *(const f32x4*)(px + j * 4);
        float am = 0.f;
#pragma unroll
        for (int j = 0; j < 4; ++j)
#pragma unroll
            for (int i = 0; i < 4; ++i) am = fmaxf(am, fabsf(v[j][i]));
#pragma unroll
        for (int off = 32; off >= 1; off >>= 1) am = fmaxf(am, __shfl_xor(am, off));
        if (lane == 0) red[wid] = am;
        __syncthreads();
        float amax = fmaxf(fmaxf(red[0], red[1]), fmaxf(red[2], red[3]));
        amax = fmaxf(amax, 1e-30f);
        const float qs = 127.0f / amax;
        int out[4];
#pragma unroll
        for (int j = 0; j < 4; ++j) {
            int b0 = ((int)rintf(v[j][0] * qs)) & 255;
            int b1 = ((int)rintf(v[j][1] * qs)) & 255;
            int b2 = ((int)rintf(v[j][2] * qs)) & 255;
            int b3 = ((int)rintf(v[j][3] * qs)) & 255;
            out[j] = b0 | (b1 << 8) | (b2 << 16) | (b3 << 24);
        }
        *(i32x4*)(Xq + (long)row * K + tid * 16) = *(i32x4*)out;
        if (tid == 0) XS[row] = amax / 127.0f;
    }
}

// ---------------- main: 256x256 pure-i8 GEMM, 16x16x64 MFMA, B tri-buffer -----
// r9 core (0 bank conflicts, tri-buffer B ledger) with PHASE-BALANCED reads:
// phases indexed (mh, ks): ph0={A(mh0,ks0)x4 + B(ks0)x4}, ph1={A(mh0,ks1)x4 +
// B(ks1)x4}, ph2={A(mh1,ks0)x4}, ph3={A(mh1,ks1)x4} -> 8/8/4/4 instead of
// 12/4/4/4. A regions 1,3 (mh1 rows 64-127/192-255) first read at ph2, after
// ph1-end vmcnt(8) drains them — ledger identical to r9:
//   entry 6 {A1A3(t), B(t+1)x4}; ph0 +A0A2(t+1); ph1 +A1A3(t+1), vmcnt(8);
//   ph2 +B0B1(t+2); ph3 +B2B3(t+2), vmcnt(6).
// Peel NT-2 (no B stage): ph3 vmcnt(2). Epilogue: ph1-end vmcnt(0) (mh1
// regions needed at ph2).
__global__ __launch_bounds__(512, 2)
void gemm_i8_kernel(const signed char* __restrict__ A,   // M x K i8
                    const signed char* __restrict__ B,   // N x K i8
                    const float* __restrict__ WS,        // N w row-scales
                    const float* __restrict__ XS,        // M x row-scales
                    const float* __restrict__ BI,
                    float* __restrict__ Y,
                    int M, int N, int K) {
    extern __shared__ char smem[];   // 163840: A @0,32768; B @65536 + b3*32768

    const int tid = threadIdx.x;
    const int lane = tid & 63;
    const int wid = tid >> 6;
    const int wr = wid >> 2;     // 0..1 (M)
    const int wc = wid & 3;      // 0..3 (N)
    const int fr = lane & 15;
    const int fq = lane >> 4;

    const int nbn = N / 256;
    const int bid = blockIdx.x;
    const int cpx = gridDim.x >> 3;
    const int wgid = (bid & 7) * cpx + (bid >> 3);   // bijective XCD swizzle
    const int tm = wgid / nbn;
    const int tn = wgid % nbn;
    const long m0 = (long)tm * 256;
    const long n0 = (long)tn * 256;

    // staging: region i covers rows [i*64, i*64+64); wave owns 8 rows (16B each).
    const int srow = wid * 8 + (lane >> 3);
    const int schunk = (lane & 7) ^ (lane >> 3);     // inverse-swz source chunk
    const signed char* gA = A + (m0 + srow) * (long)K + schunk * 16;
    const signed char* gB = B + (n0 + srow) * (long)K + schunk * 16;

    auto stageA = [&](int c2, int i, int kt) {
        GLOAD_LDS16(gA + (long)i * 64 * K + (long)kt * 128,
                    smem + c2 * 32768 + i * 8192 + wid * 1024);
    };
    auto stageB = [&](int b3, int i, int kt) {
        GLOAD_LDS16(gB + (long)i * 64 * K + (long)kt * 128,
                    smem + 65536 + b3 * 32768 + i * 8192 + wid * 1024);
    };

    const int rswz = fr & 7;    // read-side chunk ^= (row&7); row&7 == fr&7

    i32x4 acc[8][4] = {};       // [mh*4+mf][nf]
    i32x4 bfr[4][2];            // [nf][ks] — whole K-tile
    i32x4 afr[4];               // [mf] — per phase

    const int NT = K / 128;     // 32

    // prologue: B(0), A0A2(0), A1A3(0), B(1); drain to 6 outstanding
    stageB(0, 0, 0); stageB(0, 1, 0); stageB(0, 2, 0); stageB(0, 3, 0);
    stageA(0, 0, 0); stageA(0, 2, 0);
    stageA(0, 1, 0); stageA(0, 3, 0);
    stageB(1, 0, 1); stageB(1, 1, 1); stageB(1, 2, 1); stageB(1, 3, 1);
    asm volatile("s_waitcnt vmcnt(6)" ::: "memory");
    __builtin_amdgcn_s_barrier();

    for (int t = 0; t < NT - 2; ++t) {
        const char* sA = smem + (t & 1) * 32768;
        const char* sB = smem + 65536 + (t % 3) * 32768;
        const int nxtA = (t & 1) ^ 1;
        const int b2 = (t + 2) % 3;
#pragma unroll
        for (int ph = 0; ph < 4; ++ph) {
            const int ks = ph & 1;
            const int mh = ph >> 1;
#pragma unroll
            for (int mf = 0; mf < 4; ++mf) {
                int row = wr * 128 + mh * 64 + mf * 16 + fr;
                afr[mf] = *(const i32x4*)(sA + row * 128 + ((fq + 4 * ks) ^ rswz) * 16);
            }
            if (mh == 0) {
#pragma unroll
                for (int nf = 0; nf < 4; ++nf) {
                    int row = wc * 64 + nf * 16 + fr;
                    bfr[nf][ks] = *(const i32x4*)(sB + row * 128 + ((fq + 4 * ks) ^ rswz) * 16);
                }
            }
            if (ph == 0)      { stageA(nxtA, 0, t + 1); stageA(nxtA, 2, t + 1); }
            else if (ph == 1) { stageA(nxtA, 1, t + 1); stageA(nxtA, 3, t + 1); }
            else if (ph == 2) { stageB(b2, 0, t + 2); stageB(b2, 1, t + 2); }
            else              { stageB(b2, 2, t + 2); stageB(b2, 3, t + 2); }

            if (mh == 0) asm volatile("s_waitcnt lgkmcnt(4)" ::: "memory");
            __builtin_amdgcn_s_barrier();
            __builtin_amdgcn_s_setprio(1);
#pragma unroll
            for (int mf = 0; mf < 4; ++mf)
#pragma unroll
                for (int nf = 0; nf < 4; ++nf)
                    acc[mh * 4 + mf][nf] = __builtin_amdgcn_mfma_i32_16x16x64_i8(
                        afr[mf], bfr[nf][ks], acc[mh * 4 + mf][nf], 0, 0, 0);
            __builtin_amdgcn_s_setprio(0);
            if (ph == 1) asm volatile("s_waitcnt vmcnt(8)" ::: "memory");
            if (ph == 3) asm volatile("s_waitcnt vmcnt(6)" ::: "memory");
            __builtin_amdgcn_s_barrier();
        }
    }

    // peeled t = NT-2: stage A(t+1) only; ph3-end drains to 2
    {
        const int t = NT - 2;
        const char* sA = smem + (t & 1) * 32768;
        const char* sB = smem + 65536 + (t % 3) * 32768;
        const int nxtA = (t & 1) ^ 1;
#pragma unroll
        for (int ph = 0; ph < 4; ++ph) {
            const int ks = ph & 1;
            const int mh = ph >> 1;
#pragma unroll
            for (int mf = 0; mf < 4; ++mf) {
                int row = wr * 128 + mh * 64 + mf * 16 + fr;
                afr[mf] = *(const i32x4*)(sA + row * 128 + ((fq + 4 * ks) ^ rswz) * 16);
            }
            if (mh == 0) {
#pragma unroll
                for (int nf = 0; nf < 4; ++nf) {
                    int row = wc * 64 + nf * 16 + fr;
                    bfr[nf][ks] = *(const i32x4*)(sB + row * 128 + ((fq + 4 * ks) ^ rswz) * 16);
                }
            }
            if (ph == 0)      { stageA(nxtA, 0, t + 1); stageA(nxtA, 2, t + 1); }
            else if (ph == 1) { stageA(nxtA, 1, t + 1); stageA(nxtA, 3, t + 1); }

            if (mh == 0) asm volatile("s_waitcnt lgkmcnt(4)" ::: "memory");
            __builtin_amdgcn_s_barrier();
            __builtin_amdgcn_s_setprio(1);
#pragma unroll
            for (int mf = 0; mf < 4; ++mf)
#pragma unroll
                for (int nf = 0; nf < 4; ++nf)
                    acc[mh * 4 + mf][nf] = __builtin_amdgcn_mfma_i32_16x16x64_i8(
                        afr[mf], bfr[nf][ks], acc[mh * 4 + mf][nf], 0, 0, 0);
            __builtin_amdgcn_s_setprio(0);
            if (ph == 1) asm volatile("s_waitcnt vmcnt(8)" ::: "memory");
            if (ph == 3) asm volatile("s_waitcnt vmcnt(2)" ::: "memory");
            __builtin_amdgcn_s_barrier();
        }
    }

    // epilogue K-tile NT-1: no staging; ph1-end drains the leftover A1,A3
    {
        const int t = NT - 1;
        const char* sA = smem + (t & 1) * 32768;
        const char* sB = smem + 65536 + (t % 3) * 32768;
#pragma unroll
        for (int ph = 0; ph < 4; ++ph) {
            const int ks = ph & 1;
            const int mh = ph >> 1;
#pragma unroll
            for (int mf = 0; mf < 4; ++mf) {
                int row = wr * 128 + mh * 64 + mf * 16 + fr;
                afr[mf] = *(const i32x4*)(sA + row * 128 + ((fq + 4 * ks) ^ rswz) * 16);
            }
            if (mh == 0) {
#pragma unroll
                for (int nf = 0; nf < 4; ++nf) {
                    int row = wc * 64 + nf * 16 + fr;
                    bfr[nf][ks] = *(const i32x4*)(sB + row * 128 + ((fq + 4 * ks) ^ rswz) * 16);
                }
            }
            if (mh == 0) asm volatile("s_waitcnt lgkmcnt(4)" ::: "memory");
            __builtin_amdgcn_s_barrier();
            __builtin_amdgcn_s_setprio(1);
#pragma unroll
            for (int mf = 0; mf < 4; ++mf)
#pragma unroll
                for (int nf = 0; nf < 4; ++nf)
                    acc[mh * 4 + mf][nf] = __builtin_amdgcn_mfma_i32_16x16x64_i8(
                        afr[mf], bfr[nf][ks], acc[mh * 4 + mf][nf], 0, 0, 0);
            __builtin_amdgcn_s_setprio(0);
            if (ph == 1) asm volatile("s_waitcnt vmcnt(0)" ::: "memory");
            __builtin_amdgcn_s_barrier();
        }
    }

    // C-write: col=lane&15, row=4*(lane>>4)+i [m89/m91]; y = i32*XS[m]*WS[o]+b
    // acc index m = mh*4+mf -> row offset (m>>2)*64 + (m&3)*16
#pragma unroll
    for (int nf = 0; nf < 4; ++nf) {
        const long col = n0 + wc * 64 + nf * 16 + fr;
        const float ws = WS[col];
        const float bv = BI[col];
#pragma unroll
        for (int m = 0; m < 8; ++m) {
            const long rbase = m0 + wr * 128 + (m >> 2) * 64 + (m & 3) * 16 + 4 * fq;
#pragma unroll
            for (int i = 0; i < 4; ++i)
                Y[(rbase + i) * N + col] =
                    (float)acc[m][nf][i] * (XS[rbase + i] * ws) + bv;
        }
    }
}

// ---------------- fallback: fused fp32 kernel (verified round 2) ----------------
#define BM 128
#define BN 128
#define BK 64
#define PK 72

__global__ void gptq_gemm_fallback(const float* __restrict__ X,
                                   const int* __restrict__ QW,
                                   const float* __restrict__ SC,
                                   const int* __restrict__ ZR,
                                   const float* __restrict__ BI,
                                   float* __restrict__ Y,
                                   int M, int N, int K, int G) {
    __shared__ __align__(16) short As[BM * PK];
    __shared__ __align__(16) short Bs[BN * PK];

    const int tid = threadIdx.x;
    const int nbm = M / BM;
    const int bid = blockIdx.x;
    const int cpx = gridDim.x >> 3;
    const int wgid = (bid & 7) * cpx + (bid >> 3);
    const int tm = wgid % nbm;
    const int tn = wgid / nbm;
    const long m0 = (long)tm * BM;
    const long n0 = (long)tn * BN;
    const int Kp = K >> 1;

    const int lane = tid & 63;
    const int wid = tid >> 6;
    const int wr = wid >> 1;
    const int wc = wid & 1;
    const int fr = lane & 15;
    const int fq = lane >> 4;

    int srow[4], sq[4];
#pragma unroll
    for (int c = 0; c < 4; ++c) {
        int w = tid + 256 * c;
        srow[c] = w >> 3;
        sq[c] = w & 7;
    }

    f32x4 acc[4][4] = {};
    const int NT = K / BK;

    for (int kt = 0; kt < NT; ++kt) {
        const int g = (kt * BK) / GS;
        f32x4 a0[4], a1[4];
        i32x4 b4[4];
        float sc_r[4], zr_r[4];
#pragma unroll
        for (int c = 0; c < 4; ++c) {
            const float* pa = X + (m0 + srow[c]) * K + kt * BK + 8 * sq[c];
            a0[c] = *(const f32x4*)pa;
            a1[c] = *(const f32x4*)(pa + 4);
            const int* pb = QW + (n0 + srow[c]) * Kp + kt * (BK / 2) + 4 * sq[c];
            b4[c] = *(const i32x4*)pb;
            sc_r[c] = SC[(n0 + srow[c]) * G + g];
            zr_r[c] = (float)ZR[(n0 + srow[c]) * G + g];
        }
        __syncthreads();
#pragma unroll
        for (int c = 0; c < 4; ++c) {
            bf16x8 av;
#pragma unroll
            for (int i = 0; i < 4; ++i) av[i] = f2bf(a0[c][i]);
#pragma unroll
            for (int i = 0; i < 4; ++i) av[4 + i] = f2bf(a1[c][i]);
            *(bf16x8*)(As + srow[c] * PK + 8 * sq[c]) = av;
            bf16x8 bv;
#pragma unroll
            for (int j = 0; j < 4; ++j) {
                int v = b4[c][j];
                bv[2 * j]     = f2bf(((float)(v & 15) - zr_r[c]) * sc_r[c]);
                bv[2 * j + 1] = f2bf(((float)((v >> 4) & 15) - zr_r[c]) * sc_r[c]);
            }
            *(bf16x8*)(Bs + srow[c] * PK + 8 * sq[c]) = bv;
        }
        __syncthreads();
#pragma unroll
        for (int kk = 0; kk < BK; kk += 32) {
            bf16x8 a[4], b[4];
#pragma unroll
            for (int mf = 0; mf < 4; ++mf)
                a[mf] = *(const bf16x8*)(As + (wr * 64 + mf * 16 + fr) * PK + kk + 8 * fq);
#pragma unroll
            for (int nf = 0; nf < 4; ++nf)
                b[nf] = *(const bf16x8*)(Bs + (wc * 64 + nf * 16 + fr) * PK + kk + 8 * fq);
#pragma unroll
            for (int mf = 0; mf < 4; ++mf)
#pragma unroll
                for (int nf = 0; nf < 4; ++nf)
                    acc[mf][nf] = __builtin_amdgcn_mfma_f32_16x16x32_bf16(
                        a[mf], b[nf], acc[mf][nf], 0, 0, 0);
        }
    }

#pragma unroll
    for (int nf = 0; nf < 4; ++nf) {
        const long col = n0 + wc * 64 + nf * 16 + fr;
        const float bias_v = BI[col];
#pragma unroll
        for (int mf = 0; mf < 4; ++mf) {
            const long rbase = m0 + wr * 64 + mf * 16 + 4 * fq;
#pragma unroll
            for (int i = 0; i < 4; ++i)
                Y[(rbase + i) * N + col] = acc[mf][nf][i] + bias_v;
        }
    }
}

extern "C" void kernel_launch(void* const* d_in, const int* in_sizes, int n_in,
                              void* d_out, int out_size, void* d_ws, size_t ws_size,
                              hipStream_t stream) {
    const float* X = (const float*)d_in[0];
    const int* QW = (const int*)d_in[1];
    const float* SC = (const float*)d_in[2];
    const int* ZR = (const int*)d_in[3];
    const float* BI = (const float*)d_in[4];
    float* Y = (float*)d_out;

    const int N = in_sizes[4];          // 4096
    const int G = in_sizes[2] / N;      // 32
    const int K = G * GS;               // 4096
    const int M = in_sizes[0] / K;      // 8192

    const size_t needW8 = (size_t)N * K;            // int8 W
    const size_t needXq = (size_t)M * K;            // int8 X
    const size_t needXS = (size_t)M * 4;
    const size_t needWS = (size_t)N * 4;
    const size_t need = needW8 + needXq + needXS + needWS;

    if (ws_size >= need) {
        signed char* W8 = (signed char*)d_ws;
        signed char* Xq = W8 + needW8;
        float* XS = (float*)(Xq + needXq);
        float* WS = XS + M;

        hipLaunchKernelGGL(prep_kernel, dim3(N + M), dim3(256), 0, stream,
                           QW, SC, ZR, X, W8, WS, Xq, XS, N, K, G);

        (void)hipFuncSetAttribute((const void*)gemm_i8_kernel,
                                  hipFuncAttributeMaxDynamicSharedMemorySize, 163840);
        const int grid = (M / 256) * (N / 256);   // 512, % 8 == 0
        hipLaunchKernelGGL(gemm_i8_kernel, dim3(grid), dim3(512), 163840, stream,
                           Xq, W8, WS, XS, BI, Y, M, N, K);
    } else {
        const int grid = (M / BM) * (N / BN);
        hipLaunchKernelGGL(gptq_gemm_fallback, dim3(grid), dim3(256), 0, stream,
                           X, QW, SC, ZR, BI, Y, M, N, K, G);
    }
}

// Round 11
// 178.771 us; speedup vs baseline: 1.0249x; 1.0249x over previous
//
#include <hip/hip_runtime.h>
#include <hip/hip_bf16.h>

typedef __attribute__((ext_vector_type(4))) float f32x4;
typedef __attribute__((ext_vector_type(8))) short bf16x8;
typedef __attribute__((ext_vector_type(4))) int i32x4;

#define GS 128

#define GLOAD_LDS16(g, l)                                                        \
    __builtin_amdgcn_global_load_lds(                                            \
        (const __attribute__((address_space(1))) void*)(g),                      \
        (__attribute__((address_space(3))) void*)(l), 16, 0, 0)

__device__ __forceinline__ short f2bf(float f) {
    union { float f; unsigned u; } v; v.f = f;
    unsigned r = v.u + 0x7fffu + ((v.u >> 16) & 1u);
    return (short)(r >> 16);
}

// ---------------- fused prep: W requant (blocks [0,N)) + X quant (blocks [N,N+M)) ----
__global__ void prep_kernel(const int* __restrict__ QW,
                            const float* __restrict__ SC,
                            const int* __restrict__ ZR,
                            const float* __restrict__ X,
                            signed char* __restrict__ W8,
                            float* __restrict__ WS,
                            signed char* __restrict__ Xq,
                            float* __restrict__ XS,
                            int N, int K, int G) {
    const int tid = threadIdx.x;             // 256 threads
    const int lane = tid & 63;
    const int wid = tid >> 6;
    __shared__ float red[4];

    if ((int)blockIdx.x < N) {
        // ---- per-row W requant -> int8 with per-row scale ----
        const int o = blockIdx.x;
        const int g = tid / 8;               // (tid*16)/128
        const float s = SC[(long)o * G + g];
        const float z = (float)ZR[(long)o * G + g];
        const int* p = QW + (long)o * (K / 2) + tid * 8;
        int v[8];
#pragma unroll
        for (int j = 0; j < 8; ++j) v[j] = p[j];
        float w[16];
#pragma unroll
        for (int j = 0; j < 8; ++j) {
            w[2 * j]     = ((float)(v[j] & 15) - z) * s;
            w[2 * j + 1] = ((float)((v[j] >> 4) & 15) - z) * s;
        }
        float am = 0.f;
#pragma unroll
        for (int j = 0; j < 16; ++j) am = fmaxf(am, fabsf(w[j]));
#pragma unroll
        for (int off = 32; off >= 1; off >>= 1) am = fmaxf(am, __shfl_xor(am, off));
        if (lane == 0) red[wid] = am;
        __syncthreads();
        float wmax = fmaxf(fmaxf(red[0], red[1]), fmaxf(red[2], red[3]));
        wmax = fmaxf(wmax, 1e-30f);
        const float qs = 127.0f / wmax;
        int out[4];
#pragma unroll
        for (int j = 0; j < 4; ++j) {
            int b0 = ((int)rintf(w[4 * j]     * qs)) & 255;
            int b1 = ((int)rintf(w[4 * j + 1] * qs)) & 255;
            int b2 = ((int)rintf(w[4 * j + 2] * qs)) & 255;
            int b3 = ((int)rintf(w[4 * j + 3] * qs)) & 255;
            out[j] = b0 | (b1 << 8) | (b2 << 16) | (b3 << 24);
        }
        *(i32x4*)(W8 + (long)o * K + tid * 16) = *(i32x4*)out;
        if (tid == 0) WS[o] = wmax / 127.0f;
    } else {
        // ---- per-row dynamic int8 quant of X ----
        const int row = blockIdx.x - N;
        const float* px = X + (long)row * K + tid * 16;
        f32x4 v[4];
#pragma unroll
        for (int j = 0; j < 4; ++j) v[j] = *(const f32x4*)(px + j * 4);
        float am = 0.f;
#pragma unroll
        for (int j = 0; j < 4; ++j)
#pragma unroll
            for (int i = 0; i < 4; ++i) am = fmaxf(am, fabsf(v[j][i]));
#pragma unroll
        for (int off = 32; off >= 1; off >>= 1) am = fmaxf(am, __shfl_xor(am, off));
        if (lane == 0) red[wid] = am;
        __syncthreads();
        float amax = fmaxf(fmaxf(red[0], red[1]), fmaxf(red[2], red[3]));
        amax = fmaxf(amax, 1e-30f);
        const float qs = 127.0f / amax;
        int out[4];
#pragma unroll
        for (int j = 0; j < 4; ++j) {
            int b0 = ((int)rintf(v[j][0] * qs)) & 255;
            int b1 = ((int)rintf(v[j][1] * qs)) & 255;
            int b2 = ((int)rintf(v[j][2] * qs)) & 255;
            int b3 = ((int)rintf(v[j][3] * qs)) & 255;
            out[j] = b0 | (b1 << 8) | (b2 << 16) | (b3 << 24);
        }
        *(i32x4*)(Xq + (long)row * K + tid * 16) = *(i32x4*)out;
        if (tid == 0) XS[row] = amax / 127.0f;
    }
}

// ---------------- main: 256x256 pure-i8 GEMM, ONE barrier per K-tile ----------
// r10 core (0 bank conflicts, tri-buffer B) with the per-phase barriers REMOVED.
// Correctness argument (single barrier per tile, raw s_barrier + counted vmcnt):
//  - stage writes during tile t touch A[(t+1)&1] / B[(t+2)%3], last READ during
//    tile t-1; every wave passed the end-of-(t-1) barrier before entering t.
//  - reads of tile t need A(t),B(t) landed: both are drained by every wave's
//    end-of-(t-1) vmcnt(4) (in-flight after it = newest 4 = B(t+1) only),
//    and made visible by the same barrier.
// Steady ledger: entry leftover 4 {B(t+1)}; during t: +A(t+1)x4, +B(t+2)x4 =
// 12; end-of-t vmcnt(4) leaves B(t+2)x4. Peel t=NT-2: +A only -> vmcnt(0).
// Tile NT-1: compute only. Within a tile: no barriers — compiler interleaves
// ds_read/MFMA freely with its own fine-grained lgkmcnt.
__global__ __launch_bounds__(512, 2)
void gemm_i8_kernel(const signed char* __restrict__ A,   // M x K i8
                    const signed char* __restrict__ B,   // N x K i8
                    const float* __restrict__ WS,        // N w row-scales
                    const float* __restrict__ XS,        // M x row-scales
                    const float* __restrict__ BI,
                    float* __restrict__ Y,
                    int M, int N, int K) {
    extern __shared__ char smem[];   // 163840: A @0,32768; B @65536 + b3*32768

    const int tid = threadIdx.x;
    const int lane = tid & 63;
    const int wid = tid >> 6;
    const int wr = wid >> 2;     // 0..1 (M)
    const int wc = wid & 3;      // 0..3 (N)
    const int fr = lane & 15;
    const int fq = lane >> 4;

    const int nbn = N / 256;
    const int bid = blockIdx.x;
    const int cpx = gridDim.x >> 3;
    const int wgid = (bid & 7) * cpx + (bid >> 3);   // bijective XCD swizzle
    const int tm = wgid / nbn;
    const int tn = wgid % nbn;
    const long m0 = (long)tm * 256;
    const long n0 = (long)tn * 256;

    // staging: region i covers rows [i*64, i*64+64); wave owns 8 rows (16B each).
    const int srow = wid * 8 + (lane >> 3);
    const int schunk = (lane & 7) ^ (lane >> 3);     // inverse-swz source chunk
    const signed char* gA = A + (m0 + srow) * (long)K + schunk * 16;
    const signed char* gB = B + (n0 + srow) * (long)K + schunk * 16;

    auto stageA = [&](int c2, int i, int kt) {
        GLOAD_LDS16(gA + (long)i * 64 * K + (long)kt * 128,
                    smem + c2 * 32768 + i * 8192 + wid * 1024);
    };
    auto stageB = [&](int b3, int i, int kt) {
        GLOAD_LDS16(gB + (long)i * 64 * K + (long)kt * 128,
                    smem + 65536 + b3 * 32768 + i * 8192 + wid * 1024);
    };

    const int rswz = fr & 7;    // read-side chunk ^= (row&7); row&7 == fr&7

    i32x4 acc[8][4] = {};       // [mh*4+mf][nf]
    i32x4 bfr[4][2];            // [nf][ks] — whole K-tile
    i32x4 afr[4];               // [mf] — per phase

    const int NT = K / 128;     // 32

    // prologue: B(0), A(0), B(1); drain to 4 outstanding {B(1)}
    stageB(0, 0, 0); stageB(0, 1, 0); stageB(0, 2, 0); stageB(0, 3, 0);
    stageA(0, 0, 0); stageA(0, 1, 0); stageA(0, 2, 0); stageA(0, 3, 0);
    stageB(1, 0, 1); stageB(1, 1, 1); stageB(1, 2, 1); stageB(1, 3, 1);
    asm volatile("s_waitcnt vmcnt(4)" ::: "memory");
    __builtin_amdgcn_s_barrier();

    for (int t = 0; t < NT - 2; ++t) {
        const char* sA = smem + (t & 1) * 32768;
        const char* sB = smem + 65536 + (t % 3) * 32768;
        const int nxtA = (t & 1) ^ 1;
        const int b2 = (t + 2) % 3;
#pragma unroll
        for (int ph = 0; ph < 4; ++ph) {
            const int ks = ph & 1;
            const int mh = ph >> 1;
#pragma unroll
            for (int mf = 0; mf < 4; ++mf) {
                int row = wr * 128 + mh * 64 + mf * 16 + fr;
                afr[mf] = *(const i32x4*)(sA + row * 128 + ((fq + 4 * ks) ^ rswz) * 16);
            }
            if (mh == 0) {
#pragma unroll
                for (int nf = 0; nf < 4; ++nf) {
                    int row = wc * 64 + nf * 16 + fr;
                    bfr[nf][ks] = *(const i32x4*)(sB + row * 128 + ((fq + 4 * ks) ^ rswz) * 16);
                }
            }
            if (ph == 0)      { stageA(nxtA, 0, t + 1); stageA(nxtA, 2, t + 1); }
            else if (ph == 1) { stageA(nxtA, 1, t + 1); stageA(nxtA, 3, t + 1); }
            else if (ph == 2) { stageB(b2, 0, t + 2); stageB(b2, 1, t + 2); }
            else              { stageB(b2, 2, t + 2); stageB(b2, 3, t + 2); }

            __builtin_amdgcn_s_setprio(1);
#pragma unroll
            for (int mf = 0; mf < 4; ++mf)
#pragma unroll
                for (int nf = 0; nf < 4; ++nf)
                    acc[mh * 4 + mf][nf] = __builtin_amdgcn_mfma_i32_16x16x64_i8(
                        afr[mf], bfr[nf][ks], acc[mh * 4 + mf][nf], 0, 0, 0);
            __builtin_amdgcn_s_setprio(0);
        }
        // single end-of-tile sync: A(t+1),B(t+1) landed; B(t+2) stays in flight
        asm volatile("s_waitcnt vmcnt(4)" ::: "memory");
        __builtin_amdgcn_s_barrier();
    }

    // peeled t = NT-2: stage A(t+1) only; end drains everything
    {
        const int t = NT - 2;
        const char* sA = smem + (t & 1) * 32768;
        const char* sB = smem + 65536 + (t % 3) * 32768;
        const int nxtA = (t & 1) ^ 1;
#pragma unroll
        for (int ph = 0; ph < 4; ++ph) {
            const int ks = ph & 1;
            const int mh = ph >> 1;
#pragma unroll
            for (int mf = 0; mf < 4; ++mf) {
                int row = wr * 128 + mh * 64 + mf * 16 + fr;
                afr[mf] = *(const i32x4*)(sA + row * 128 + ((fq + 4 * ks) ^ rswz) * 16);
            }
            if (mh == 0) {
#pragma unroll
                for (int nf = 0; nf < 4; ++nf) {
                    int row = wc * 64 + nf * 16 + fr;
                    bfr[nf][ks] = *(const i32x4*)(sB + row * 128 + ((fq + 4 * ks) ^ rswz) * 16);
                }
            }
            if (ph == 0)      { stageA(nxtA, 0, t + 1); stageA(nxtA, 2, t + 1); }
            else if (ph == 1) { stageA(nxtA, 1, t + 1); stageA(nxtA, 3, t + 1); }

            __builtin_amdgcn_s_setprio(1);
#pragma unroll
            for (int mf = 0; mf < 4; ++mf)
#pragma unroll
                for (int nf = 0; nf < 4; ++nf)
                    acc[mh * 4 + mf][nf] = __builtin_amdgcn_mfma_i32_16x16x64_i8(
                        afr[mf], bfr[nf][ks], acc[mh * 4 + mf][nf], 0, 0, 0);
            __builtin_amdgcn_s_setprio(0);
        }
        asm volatile("s_waitcnt vmcnt(0)" ::: "memory");
        __builtin_amdgcn_s_barrier();
    }

    // epilogue K-tile NT-1: compute only
    {
        const int t = NT - 1;
        const char* sA = smem + (t & 1) * 32768;
        const char* sB = smem + 65536 + (t % 3) * 32768;
#pragma unroll
        for (int ph = 0; ph < 4; ++ph) {
            const int ks = ph & 1;
            const int mh = ph >> 1;
#pragma unroll
            for (int mf = 0; mf < 4; ++mf) {
                int row = wr * 128 + mh * 64 + mf * 16 + fr;
                afr[mf] = *(const i32x4*)(sA + row * 128 + ((fq + 4 * ks) ^ rswz) * 16);
            }
            if (mh == 0) {
#pragma unroll
                for (int nf = 0; nf < 4; ++nf) {
                    int row = wc * 64 + nf * 16 + fr;
                    bfr[nf][ks] = *(const i32x4*)(sB + row * 128 + ((fq + 4 * ks) ^ rswz) * 16);
                }
            }
            __builtin_amdgcn_s_setprio(1);
#pragma unroll
            for (int mf = 0; mf < 4; ++mf)
#pragma unroll
                for (int nf = 0; nf < 4; ++nf)
                    acc[mh * 4 + mf][nf] = __builtin_amdgcn_mfma_i32_16x16x64_i8(
                        afr[mf], bfr[nf][ks], acc[mh * 4 + mf][nf], 0, 0, 0);
            __builtin_amdgcn_s_setprio(0);
        }
    }

    // C-write: col=lane&15, row=4*(lane>>4)+i [m89/m91]; y = i32*XS[m]*WS[o]+b
    // acc index m = mh*4+mf -> row offset (m>>2)*64 + (m&3)*16
#pragma unroll
    for (int nf = 0; nf < 4; ++nf) {
        const long col = n0 + wc * 64 + nf * 16 + fr;
        const float ws = WS[col];
        const float bv = BI[col];
#pragma unroll
        for (int m = 0; m < 8; ++m) {
            const long rbase = m0 + wr * 128 + (m >> 2) * 64 + (m & 3) * 16 + 4 * fq;
#pragma unroll
            for (int i = 0; i < 4; ++i)
                Y[(rbase + i) * N + col] =
                    (float)acc[m][nf][i] * (XS[rbase + i] * ws) + bv;
        }
    }
}

// ---------------- fallback: fused fp32 kernel (verified round 2) ----------------
#define BM 128
#define BN 128
#define BK 64
#define PK 72

__global__ void gptq_gemm_fallback(const float* __restrict__ X,
                                   const int* __restrict__ QW,
                                   const float* __restrict__ SC,
                                   const int* __restrict__ ZR,
                                   const float* __restrict__ BI,
                                   float* __restrict__ Y,
                                   int M, int N, int K, int G) {
    __shared__ __align__(16) short As[BM * PK];
    __shared__ __align__(16) short Bs[BN * PK];

    const int tid = threadIdx.x;
    const int nbm = M / BM;
    const int bid = blockIdx.x;
    const int cpx = gridDim.x >> 3;
    const int wgid = (bid & 7) * cpx + (bid >> 3);
    const int tm = wgid % nbm;
    const int tn = wgid / nbm;
    const long m0 = (long)tm * BM;
    const long n0 = (long)tn * BN;
    const int Kp = K >> 1;

    const int lane = tid & 63;
    const int wid = tid >> 6;
    const int wr = wid >> 1;
    const int wc = wid & 1;
    const int fr = lane & 15;
    const int fq = lane >> 4;

    int srow[4], sq[4];
#pragma unroll
    for (int c = 0; c < 4; ++c) {
        int w = tid + 256 * c;
        srow[c] = w >> 3;
        sq[c] = w & 7;
    }

    f32x4 acc[4][4] = {};
    const int NT = K / BK;

    for (int kt = 0; kt < NT; ++kt) {
        const int g = (kt * BK) / GS;
        f32x4 a0[4], a1[4];
        i32x4 b4[4];
        float sc_r[4], zr_r[4];
#pragma unroll
        for (int c = 0; c < 4; ++c) {
            const float* pa = X + (m0 + srow[c]) * K + kt * BK + 8 * sq[c];
            a0[c] = *(const f32x4*)pa;
            a1[c] = *(const f32x4*)(pa + 4);
            const int* pb = QW + (n0 + srow[c]) * Kp + kt * (BK / 2) + 4 * sq[c];
            b4[c] = *(const i32x4*)pb;
            sc_r[c] = SC[(n0 + srow[c]) * G + g];
            zr_r[c] = (float)ZR[(n0 + srow[c]) * G + g];
        }
        __syncthreads();
#pragma unroll
        for (int c = 0; c < 4; ++c) {
            bf16x8 av;
#pragma unroll
            for (int i = 0; i < 4; ++i) av[i] = f2bf(a0[c][i]);
#pragma unroll
            for (int i = 0; i < 4; ++i) av[4 + i] = f2bf(a1[c][i]);
            *(bf16x8*)(As + srow[c] * PK + 8 * sq[c]) = av;
            bf16x8 bv;
#pragma unroll
            for (int j = 0; j < 4; ++j) {
                int v = b4[c][j];
                bv[2 * j]     = f2bf(((float)(v & 15) - zr_r[c]) * sc_r[c]);
                bv[2 * j + 1] = f2bf(((float)((v >> 4) & 15) - zr_r[c]) * sc_r[c]);
            }
            *(bf16x8*)(Bs + srow[c] * PK + 8 * sq[c]) = bv;
        }
        __syncthreads();
#pragma unroll
        for (int kk = 0; kk < BK; kk += 32) {
            bf16x8 a[4], b[4];
#pragma unroll
            for (int mf = 0; mf < 4; ++mf)
                a[mf] = *(const bf16x8*)(As + (wr * 64 + mf * 16 + fr) * PK + kk + 8 * fq);
#pragma unroll
            for (int nf = 0; nf < 4; ++nf)
                b[nf] = *(const bf16x8*)(Bs + (wc * 64 + nf * 16 + fr) * PK + kk + 8 * fq);
#pragma unroll
            for (int mf = 0; mf < 4; ++mf)
#pragma unroll
                for (int nf = 0; nf < 4; ++nf)
                    acc[mf][nf] = __builtin_amdgcn_mfma_f32_16x16x32_bf16(
                        a[mf], b[nf], acc[mf][nf], 0, 0, 0);
        }
    }

#pragma unroll
    for (int nf = 0; nf < 4; ++nf) {
        const long col = n0 + wc * 64 + nf * 16 + fr;
        const float bias_v = BI[col];
#pragma unroll
        for (int mf = 0; mf < 4; ++mf) {
            const long rbase = m0 + wr * 64 + mf * 16 + 4 * fq;
#pragma unroll
            for (int i = 0; i < 4; ++i)
                Y[(rbase + i) * N + col] = acc[mf][nf][i] + bias_v;
        }
    }
}

extern "C" void kernel_launch(void* const* d_in, const int* in_sizes, int n_in,
                              void* d_out, int out_size, void* d_ws, size_t ws_size,
                              hipStream_t stream) {
    const float* X = (const float*)d_in[0];
    const int* QW = (const int*)d_in[1];
    const float* SC = (const float*)d_in[2];
    const int* ZR = (const int*)d_in[3];
    const float* BI = (const float*)d_in[4];
    float* Y = (float*)d_out;

    const int N = in_sizes[4];          // 4096
    const int G = in_sizes[2] / N;      // 32
    const int K = G * GS;               // 4096
    const int M = in_sizes[0] / K;      // 8192

    const size_t needW8 = (size_t)N * K;            // int8 W
    const size_t needXq = (size_t)M * K;            // int8 X
    const size_t needXS = (size_t)M * 4;
    const size_t needWS = (size_t)N * 4;
    const size_t need = needW8 + needXq + needXS + needWS;

    if (ws_size >= need) {
        signed char* W8 = (signed char*)d_ws;
        signed char* Xq = W8 + needW8;
        float* XS = (float*)(Xq + needXq);
        float* WS = XS + M;

        hipLaunchKernelGGL(prep_kernel, dim3(N + M), dim3(256), 0, stream,
                           QW, SC, ZR, X, W8, WS, Xq, XS, N, K, G);

        (void)hipFuncSetAttribute((const void*)gemm_i8_kernel,
                                  hipFuncAttributeMaxDynamicSharedMemorySize, 163840);
        const int grid = (M / 256) * (N / 256);   // 512, % 8 == 0
        hipLaunchKernelGGL(gemm_i8_kernel, dim3(grid), dim3(512), 163840, stream,
                           Xq, W8, WS, XS, BI, Y, M, N, K);
    } else {
        const int grid = (M / BM) * (N / BN);
        hipLaunchKernelGGL(gptq_gemm_fallback, dim3(grid), dim3(256), 0, stream,
                           X, QW, SC, ZR, BI, Y, M, N, K, G);
    }
}